// Round 21
// baseline (129.054 us; speedup 1.0000x reference)
//
#include <hip/hip_runtime.h>
#include <hip/hip_bf16.h>
#include <stdint.h>

typedef unsigned short u16;
typedef short bf16x8 __attribute__((ext_vector_type(8)));
typedef float f32x4 __attribute__((ext_vector_type(4)));
typedef float f32x16 __attribute__((ext_vector_type(16)));
typedef u16 u16x4 __attribute__((ext_vector_type(4)));
typedef unsigned int uint2v __attribute__((ext_vector_type(2)));

#define DIMX  1024
#define NHEAD 16
#define DH    64
#define INNER 1024
#define BATCH 2
#define SEQ   2048
#define MTOT  (BATCH*SEQ)   /* 4096 */
#define EQKV  (3*INNER)     /* 3072 */
// frag-shuffled K/V layout: [bh][t(32)][c(2)][kd(4)][lane(64)][e(8)] bf16
#define HSTRIDE 131072      /* elems per head = SEQ*DH */
#define TSTRIDE 4096        /* elems per 64-kv tile */

__device__ __forceinline__ u16 f2bf(float f) {
  unsigned int x = __float_as_uint(f);
  unsigned int r = (x + 0x7FFFu + ((x >> 16) & 1u)) >> 16;
  return (u16)r;
}

__device__ __forceinline__ unsigned int cvtpk(float lo, float hi) {
  unsigned int r;
  asm("v_cvt_pk_bf16_f32 %0, %1, %2" : "=v"(r) : "v"(lo), "v"(hi));
  return r;
}

__device__ __forceinline__ void plswap_u(unsigned int& x, unsigned int& y) {
  auto r = __builtin_amdgcn_permlane32_swap(x, y, false, false);
  x = r[0]; y = r[1];
}
__device__ __forceinline__ void plswap_f2(float v, float& a, float& b) {
  unsigned int x = __float_as_uint(v), y = __float_as_uint(v);
  auto r = __builtin_amdgcn_permlane32_swap(x, y, false, false);
  a = __uint_as_float(r[0]); b = __uint_as_float(r[1]);
}

__device__ __forceinline__ void async16(void* lds, const void* g) {
  __builtin_amdgcn_global_load_lds(
      (const __attribute__((address_space(1))) unsigned int*)g,
      (__attribute__((address_space(3))) unsigned int*)lds,
      16, 0, 0);
}

// staging swizzle (BK=32 GEMMs): 4 16B-units per 32-col row, unit ^= S(r)
__device__ __forceinline__ int swz4(int r) { return (r ^ (r >> 2)) & 3; }

// ---------------- fused fp32 -> bf16 convert (one launch, three tensors) ----------------
#define X4C (MTOT * DIMX / 4)
#define W4C (EQKV * DIMX / 4)
#define O4C (DIMX * INNER / 4)
__global__ void cvt_all(const float* __restrict__ x, const float* __restrict__ wq,
                        const float* __restrict__ wo, u16* __restrict__ xb,
                        u16* __restrict__ wqb, u16* __restrict__ wob) {
  int i = blockIdx.x * blockDim.x + threadIdx.x;
  const float* src; u16* dst; int off;
  if (i < X4C)            { src = x;  dst = xb;  off = i; }
  else if (i < X4C + W4C) { src = wq; dst = wqb; off = i - X4C; }
  else                    { src = wo; dst = wob; off = i - X4C - W4C; }
  float4 v = ((const float4*)src)[off];
  u16x4 o;
  o[0] = f2bf(v.x); o[1] = f2bf(v.y); o[2] = f2bf(v.z); o[3] = f2bf(v.w);
  ((u16x4*)dst)[off] = o;
}

// ---------------- QKV projection GEMM (r18 fenced pipeline; K/V epilogues write frag order — r20 proven) ----------------
__global__ __launch_bounds__(256) void gemm_qkv(const u16* __restrict__ X, const u16* __restrict__ W,
                                                u16* __restrict__ Qo, u16* __restrict__ Ko,
                                                u16* __restrict__ Vt) {
  __shared__ short sAll[24576];      // 48 KB: sA[3][4096] + sB[3][4096]
  short* sA = sAll;
  short* sB = sAll + 12288;
  const int tid = threadIdx.x;
  const int wv = tid >> 6, l = tid & 63;
  const int lo = l & 15, hi = l >> 4;
  const int wr = wv >> 1, wc = wv & 1;

  int lin = blockIdx.x;
  int wgid = (lin & 7) * 96 + (lin >> 3);
  const int bx = wgid / 32;
  const int by = wgid % 32;
  const int tn = bx * 128, tm = by * 128;

  f32x4 acc[4][4];
#pragma unroll
  for (int i = 0; i < 4; i++)
#pragma unroll
    for (int j = 0; j < 4; j++) acc[i][j] = (f32x4){0.f, 0.f, 0.f, 0.f};

  auto stageT = [&](int buf, int kt) {
    int k0 = kt * 32;
    int off = buf * 4096;
#pragma unroll
    for (int c = 0; c < 2; c++) {
      int R0 = wv * 32 + c * 16;
      int r = R0 + (l >> 2);
      int sc = ((l & 3) ^ swz4(r)) * 8;
      async16(&sA[off + R0 * 32], &X[(size_t)(tm + r) * DIMX + k0 + sc]);
      async16(&sB[off + R0 * 32], &W[(size_t)(tn + r) * DIMX + k0 + sc]);
    }
  };

  auto compute = [&](int buf) {
    bf16x8 af[4], bf[4];
#pragma unroll
    for (int i = 0; i < 4; i++) {
      int r = wr * 64 + i * 16 + lo;
      af[i] = *(const bf16x8*)&sA[buf * 4096 + r * 32 + ((hi ^ swz4(r)) * 8)];
    }
#pragma unroll
    for (int j = 0; j < 4; j++) {
      int r = wc * 64 + j * 16 + lo;
      bf[j] = *(const bf16x8*)&sB[buf * 4096 + r * 32 + ((hi ^ swz4(r)) * 8)];
    }
#pragma unroll
    for (int i = 0; i < 4; i++)
#pragma unroll
      for (int j = 0; j < 4; j++)
        acc[i][j] = __builtin_amdgcn_mfma_f32_16x16x32_bf16(af[i], bf[j], acc[i][j], 0, 0, 0);
  };

  const int NT = DIMX / 32;   // 32
  stageT(0, 0);
  stageT(1, 1);
  int bc = 0;
  for (int kt = 0; kt < NT - 2; kt++) {
    int bs = bc + 2; if (bs >= 3) bs -= 3;
    stageT(bs, kt + 2);
    asm volatile("s_waitcnt vmcnt(8)" ::: "memory");
    asm volatile("s_barrier" ::: "memory");
    __builtin_amdgcn_sched_barrier(0);
    compute(bc);
    __builtin_amdgcn_sched_barrier(0);
    asm volatile("s_barrier" ::: "memory");
    bc = (bc == 2) ? 0 : bc + 1;
  }
  asm volatile("s_waitcnt vmcnt(4)" ::: "memory");
  asm volatile("s_barrier" ::: "memory");
  __builtin_amdgcn_sched_barrier(0);
  compute(bc);
  __builtin_amdgcn_sched_barrier(0);
  asm volatile("s_barrier" ::: "memory");
  bc = (bc == 2) ? 0 : bc + 1;
  asm volatile("s_waitcnt vmcnt(0)" ::: "memory");
  asm volatile("s_barrier" ::: "memory");
  __builtin_amdgcn_sched_barrier(0);
  compute(bc);
  __builtin_amdgcn_sched_barrier(0);
  __syncthreads();

  const int cls = tn >> 10;
  const float scale = 0.125f * 1.44269504088896f;  // dh^-0.5 * log2(e)

  if (cls == 0) {
#pragma unroll
    for (int i = 0; i < 4; i++) {
      int mbase = tm + wr * 64 + i * 16 + hi * 4;
#pragma unroll
      for (int j = 0; j < 4; j++) {
        int e = tn + wc * 64 + j * 16 + lo;
        int h = e >> 6, d = e & 63;
        size_t a0 = (((size_t)((mbase >> 11) * NHEAD + h)) * SEQ) * DH + d;
#pragma unroll
        for (int rp = 0; rp < 2; rp++) {
          int n0 = (mbase + rp * 2) & 2047;
          unsigned int pk = cvtpk(acc[i][j][rp * 2] * scale, acc[i][j][rp * 2 + 1] * scale);
          Qo[a0 + (size_t)n0 * DH] = (u16)pk;
          Qo[a0 + (size_t)(n0 + 1) * DH] = (u16)(pk >> 16);
        }
      }
    }
  } else if (cls == 1) {
    // K: frag-shuffled scatter [bh][t][c][kd][lane][e]
#pragma unroll
    for (int i = 0; i < 4; i++) {
      int mbase = tm + wr * 64 + i * 16 + hi * 4;
      int b = mbase >> 11;
#pragma unroll
      for (int j = 0; j < 4; j++) {
        int e2 = (tn + wc * 64 + j * 16 + lo) - 1024;
        int h = e2 >> 6, d = e2 & 63;
        int kd = d >> 4, hi5k = (d >> 3) & 1, e8 = d & 7;
        size_t hb = (size_t)(b * NHEAD + h) * HSTRIDE + (size_t)kd * 512 + hi5k * 256 + e8;
#pragma unroll
        for (int rp = 0; rp < 2; rp++) {
          int n0 = (mbase + rp * 2) & 2047;
          int t_ = n0 >> 6, kvi = n0 & 63;
          int c = kvi >> 5, l31k = kvi & 31;
          unsigned int pk = cvtpk(acc[i][j][rp * 2], acc[i][j][rp * 2 + 1]);
          size_t a = hb + (size_t)t_ * TSTRIDE + c * 2048 + l31k * 8;
          Ko[a] = (u16)pk;
          Ko[a + 8] = (u16)(pk >> 16);
        }
      }
    }
  } else {
    // V: LDS bounce, then exact 16B frag-slot writes
#pragma unroll
    for (int i = 0; i < 4; i++) {
#pragma unroll
      for (int j = 0; j < 4; j++) {
        int e = wc * 64 + j * 16 + lo;
#pragma unroll
        for (int rp = 0; rp < 2; rp++) {
          int n = wr * 64 + i * 16 + hi * 4 + rp * 2;
          unsigned int pk = cvtpk(acc[i][j][rp * 2], acc[i][j][rp * 2 + 1]);
          *(unsigned int*)&sAll[e * 128 + (((n >> 3) ^ (e & 15)) * 8) + (n & 7)] = pk;
        }
      }
    }
    __syncthreads();
    int er = tid >> 1, half = tid & 1;
    int e2 = tn + er - 2048;
    int h = e2 >> 6, dv = e2 & 63;
    int b = tm >> 11, nb = tm & 2047;
    int c = dv >> 5, l31v = dv & 31;
    size_t vb = (size_t)(b * NHEAD + h) * HSTRIDE
              + (size_t)((nb >> 6) + half) * TSTRIDE + (size_t)c * 2048 + l31v * 8;
#pragma unroll
    for (int k = 0; k < 8; k++) {
      int phys = (half * 8 + k) ^ (er & 15);
      bf16x8 v = *(const bf16x8*)&sAll[er * 128 + phys * 8];
      int ks = k >> 1, hi5v = k & 1;
      *(bf16x8*)&Vt[vb + ks * 512 + hi5v * 256] = v;
    }
  }
}

// ---------------- flash attention: frag-shuffled direct-L2 + split-KV x2 ----------------
// r20 structure (no LDS, no barriers, reg-pipelined frag loads) x r11 split
// (each block covers 16 of 32 kv-tiles; partials = normalized bf16 O^T + LSE).
// 1024 blocks -> 4 waves/SIMD (VGPR 108 <= 128): double TLP for latency hiding.
__global__ __launch_bounds__(256) void attn_kernel(const u16* __restrict__ Q, const u16* __restrict__ Ksh,
                                                   const u16* __restrict__ Vsh,
                                                   u16* __restrict__ OpA, u16* __restrict__ OpB,
                                                   float* __restrict__ LseA, float* __restrict__ LseB) {
  const int tid = threadIdx.x, wv = tid >> 6, l = tid & 63;
  const int l31 = l & 31, hi5 = l >> 5;

  // XCD swizzle: 1024 blocks, 128/XCD -> 4 heads per XCD
  int lin = blockIdx.y * gridDim.x + blockIdx.x;
  int wgid = (lin & 7) * 128 + (lin >> 3);
  int bh = wgid >> 5;
  int rest = wgid & 31;
  int bx = rest >> 1;
  int half = rest & 1;

  const int qw = bx * 128 + wv * 32;
  const u16* Qb = Q + (size_t)bh * SEQ * DH;
  const u16* Kb = Ksh + (size_t)bh * HSTRIDE + l * 8;
  const u16* Vb = Vsh + (size_t)bh * HSTRIDE + l * 8;

  bf16x8 qf[4];
#pragma unroll
  for (int kd = 0; kd < 4; kd++)
    qf[kd] = *(const bf16x8*)&Qb[(size_t)(qw + l31) * DH + kd * 16 + hi5 * 8];

  f32x16 o0, o1;
#pragma unroll
  for (int r = 0; r < 16; r++) { o0[r] = 0.f; o1[r] = 0.f; }
  float lsum = 0.f;
  const float CSHIFT = 12.0f;

  bf16x8 kA0[4], kA1[4], kB0[4], kB1[4];
  const int t0 = half * 16, t1 = t0 + 16;

  auto loadK = [&](bf16x8 (&k0)[4], bf16x8 (&k1)[4], int t) {
    const u16* p = Kb + (size_t)t * TSTRIDE;
#pragma unroll
    for (int kd = 0; kd < 4; kd++) {
      k0[kd] = *(const bf16x8*)&p[kd * 512];
      k1[kd] = *(const bf16x8*)&p[2048 + kd * 512];
    }
  };

  auto tile = [&](bf16x8 (&kc0)[4], bf16x8 (&kc1)[4],
                  bf16x8 (&kn0)[4], bf16x8 (&kn1)[4], int t) {
    const u16* pv = Vb + (size_t)t * TSTRIDE;
    bf16x8 vf0[4], vf1[4];
#pragma unroll
    for (int ks = 0; ks < 4; ks++) {
      vf0[ks] = *(const bf16x8*)&pv[ks * 512];
      vf1[ks] = *(const bf16x8*)&pv[2048 + ks * 512];
    }
    if (t + 1 < t1) loadK(kn0, kn1, t + 1);

    // ---- S^T = K Q^T - CSHIFT ----
    f32x16 s0, s1;
#pragma unroll
    for (int r = 0; r < 16; r++) { s0[r] = -CSHIFT; s1[r] = -CSHIFT; }
#pragma unroll
    for (int kd = 0; kd < 4; kd++) {
      s0 = __builtin_amdgcn_mfma_f32_32x32x16_bf16(kc0[kd], qf[kd], s0, 0, 0, 0);
      s1 = __builtin_amdgcn_mfma_f32_32x32x16_bf16(kc1[kd], qf[kd], s1, 0, 0, 0);
    }

    // ---- bounded softmax: P = exp2(S - 12), no max tracking ----
    float sm[16];
#pragma unroll
    for (int r = 0; r < 16; r++) {
      s0[r] = __builtin_amdgcn_exp2f(s0[r]);
      s1[r] = __builtin_amdgcn_exp2f(s1[r]);
      sm[r] = s0[r] + s1[r];
    }
#pragma unroll
    for (int st = 8; st > 0; st >>= 1)
#pragma unroll
      for (int r = 0; r < st; r++) sm[r] += sm[r + st];
    lsum += sm[0];

    // ---- P -> PV B-frags via cvt_pk + permlane32_swap ----
    bf16x8 pa[4];
#pragma unroll
    for (int ks = 0; ks < 4; ks++) {
      const int sft = (ks & 1) * 8;
      float e0 = (ks < 2) ? s0[sft + 0] : s1[sft + 0];
      float e1 = (ks < 2) ? s0[sft + 1] : s1[sft + 1];
      float e2 = (ks < 2) ? s0[sft + 2] : s1[sft + 2];
      float e3 = (ks < 2) ? s0[sft + 3] : s1[sft + 3];
      float e4 = (ks < 2) ? s0[sft + 4] : s1[sft + 4];
      float e5 = (ks < 2) ? s0[sft + 5] : s1[sft + 5];
      float e6 = (ks < 2) ? s0[sft + 6] : s1[sft + 6];
      float e7 = (ks < 2) ? s0[sft + 7] : s1[sft + 7];
      unsigned int w0 = cvtpk(e0, e1);
      unsigned int w1 = cvtpk(e2, e3);
      unsigned int w2 = cvtpk(e4, e5);
      unsigned int w3 = cvtpk(e6, e7);
      plswap_u(w0, w2);
      plswap_u(w1, w3);
      union { unsigned int w[4]; bf16x8 v; } u;
      u.w[0] = w0; u.w[1] = w1; u.w[2] = w2; u.w[3] = w3;
      pa[ks] = u.v;
    }

    // ---- O^T += V^T P^T ----
#pragma unroll
    for (int ks = 0; ks < 4; ks++) {
      o0 = __builtin_amdgcn_mfma_f32_32x32x16_bf16(vf0[ks], pa[ks], o0, 0, 0, 0);
      o1 = __builtin_amdgcn_mfma_f32_32x32x16_bf16(vf1[ks], pa[ks], o1, 0, 0, 0);
    }
  };

  loadK(kA0, kA1, t0);
  for (int t = t0; t < t1; t += 2) {
    tile(kA0, kA1, kB0, kB1, t);
    tile(kB0, kB1, kA0, kA1, t + 1);
  }

  // ---- epilogue: normalized bf16 partial + LSE (log2 domain) ----
  float la, lb;
  plswap_f2(lsum, la, lb);
  float lt = la + lb;
  float inv = 1.0f / lt;
  float lse = CSHIFT + __log2f(lt);

  u16* Op = half ? OpB : OpA;
  float* Lse = half ? LseB : LseA;
  int q = qw + l31;
  if (hi5 == 0) Lse[(size_t)bh * SEQ + q] = lse;

  u16* Obase = Op + (size_t)bh * DH * SEQ;   // [dv][q]
#pragma unroll
  for (int r = 0; r < 16; r++) {
    int dv = (r & 3) + 8 * (r >> 2) + 4 * hi5;
    Obase[(size_t)dv * SEQ + q] = f2bf(o0[r] * inv);
    Obase[(size_t)(dv + 32) * SEQ + q] = f2bf(o1[r] * inv);
  }
}

// ---------------- split-KV merge: O = lerp(Oa, Ob, sigma(LSE)) — r10/r11 proven ----------------
__global__ __launch_bounds__(256) void merge_kernel(const u16* __restrict__ OpA, const u16* __restrict__ OpB,
                                                    const float* __restrict__ LseA, const float* __restrict__ LseB,
                                                    u16* __restrict__ O) {
  __shared__ float lsA[64 * 65];
  __shared__ float lsB[64 * 65];
  const int tid = threadIdx.x;
  const int bh = blockIdx.y, qc = blockIdx.x;
  const int b = bh >> 4, h = bh & 15;

#pragma unroll
  for (int i = 0; i < 2; i++) {
    int idx = tid + i * 256;
    int dv = idx >> 3, q8 = (idx & 7) * 8;
    size_t goff = (size_t)bh * DH * SEQ + (size_t)dv * SEQ + qc * 64 + q8;
    bf16x8 va = *(const bf16x8*)&OpA[goff];
    bf16x8 vb = *(const bf16x8*)&OpB[goff];
#pragma unroll
    for (int j = 0; j < 8; j++) {
      lsA[dv * 65 + q8 + j] = __uint_as_float(((unsigned int)(u16)va[j]) << 16);
      lsB[dv * 65 + q8 + j] = __uint_as_float(((unsigned int)(u16)vb[j]) << 16);
    }
  }
  __syncthreads();

  const int lane = tid & 63, w = tid >> 6;
#pragma unroll
  for (int i = 0; i < 16; i++) {
    int ql = w * 16 + i;
    int q = qc * 64 + ql;
    float la = LseA[(size_t)bh * SEQ + q];
    float lb = LseB[(size_t)bh * SEQ + q];
    float sig = 1.0f / (1.0f + __builtin_amdgcn_exp2f(lb - la));
    float va = lsA[lane * 65 + ql];
    float vb = lsB[lane * 65 + ql];
    float out = vb + (va - vb) * sig;
    O[((size_t)(b * SEQ + q)) * INNER + h * 64 + lane] = f2bf(out);
  }
}

// ---------------- output projection GEMM (128x64 tile, 512 blocks = 2/CU, dbuf — r17 proven) ----------------
__global__ __launch_bounds__(256) void gemm_out(const u16* __restrict__ A, const u16* __restrict__ W,
                                                const float* __restrict__ bias, float* __restrict__ out) {
  __shared__ short sAll[12288];      // sA[2][4096] + sB[2][2048]  (24 KB)
  short* sA = sAll;
  short* sB = sAll + 8192;
  const int tid = threadIdx.x;
  const int wv = tid >> 6, l = tid & 63;
  const int lo = l & 15, hi = l >> 4;
  const int wr = wv >> 1, wc = wv & 1;

  int lin = blockIdx.x;
  int wgid = (lin & 7) * 64 + (lin >> 3);
  const int bx = wgid / 32;          // N-tile 0..15
  const int by = wgid % 32;          // M-tile 0..31
  const int tn = bx * 64, tm = by * 128;

  f32x4 acc[4][2];
#pragma unroll
  for (int i = 0; i < 4; i++)
#pragma unroll
    for (int j = 0; j < 2; j++) acc[i][j] = (f32x4){0.f, 0.f, 0.f, 0.f};

  auto stage = [&](int buf, int kt) {
    int k0 = kt * 32;
#pragma unroll
    for (int c = 0; c < 2; c++) {
      int R0 = wv * 32 + c * 16;
      int r = R0 + (l >> 2);
      int sc = ((l & 3) ^ swz4(r)) * 8;
      async16(&sA[buf * 4096 + R0 * 32], &A[(size_t)(tm + r) * INNER + k0 + sc]);
    }
    int rB = wv * 16 + (l >> 2);
    int scB = ((l & 3) ^ swz4(rB)) * 8;
    async16(&sB[buf * 2048 + (wv * 16) * 32], &W[(size_t)(tn + rB) * INNER + k0 + scB]);
  };

  stage(0, 0);
  __syncthreads();

  for (int kt = 0; kt < INNER / 32; kt++) {
    const int buf = kt & 1;
    if (kt + 1 < INNER / 32) stage(buf ^ 1, kt + 1);
    bf16x8 af[4], bf[2];
#pragma unroll
    for (int i = 0; i < 4; i++) {
      int r = wr * 64 + i * 16 + lo;
      af[i] = *(const bf16x8*)&sA[buf * 4096 + r * 32 + ((hi ^ swz4(r)) * 8)];
    }
#pragma unroll
    for (int j = 0; j < 2; j++) {
      int r = wc * 32 + j * 16 + lo;
      bf[j] = *(const bf16x8*)&sB[buf * 2048 + r * 32 + ((hi ^ swz4(r)) * 8)];
    }
#pragma unroll
    for (int i = 0; i < 4; i++)
#pragma unroll
      for (int j = 0; j < 2; j++)
        acc[i][j] = __builtin_amdgcn_mfma_f32_16x16x32_bf16(af[i], bf[j], acc[i][j], 0, 0, 0);
    __syncthreads();
  }

#pragma unroll
  for (int i = 0; i < 4; i++) {
    int mbase = tm + wr * 64 + i * 16 + hi * 4;
#pragma unroll
    for (int j = 0; j < 2; j++) {
      int col = tn + wc * 32 + j * 16 + lo;
      float bv = bias[col];
#pragma unroll
      for (int r = 0; r < 4; r++)
        out[(size_t)(mbase + r) * DIMX + col] = acc[i][j][r] + bv;
    }
  }
}

extern "C" void kernel_launch(void* const* d_in, const int* in_sizes, int n_in,
                              void* d_out, int out_size, void* d_ws, size_t ws_size,
                              hipStream_t stream) {
  const float* x     = (const float*)d_in[0];
  const float* w_qkv = (const float*)d_in[1];
  const float* w_out = (const float*)d_in[2];
  const float* b_out = (const float*)d_in[3];

  char* ws = (char*)d_ws;
  u16* xb    = (u16*)(ws);                         // 8 MB (dead after gemm_qkv)
  u16* wqkvb = (u16*)(ws + (size_t)8  * (1<<20));  // 6 MB (dead after gemm_qkv)
  u16* woutb = (u16*)(ws + (size_t)14 * (1<<20));  // 2 MB
  u16* Qd    = (u16*)(ws + (size_t)16 * (1<<20));  // 8 MB
  u16* Kdd   = (u16*)(ws + (size_t)24 * (1<<20));  // 8 MB (frag-shuffled)
  u16* Vtd   = (u16*)(ws + (size_t)32 * (1<<20));  // 8 MB (frag-shuffled)
  u16* Od    = (u16*)(ws + (size_t)40 * (1<<20));  // 8 MB
  u16*   OpA  = (u16*)(ws);                        // 8 MB, over xb
  u16*   OpB  = (u16*)(ws + (size_t)48 * (1<<20)); // 8 MB
  float* LseA = (float*)(ws + (size_t)8 * (1<<20));            // 256 KB, over wqkvb
  float* LseB = (float*)(ws + (size_t)8 * (1<<20) + (1<<19));  // 256 KB

  cvt_all<<<(X4C + W4C + O4C) / 256, 256, 0, stream>>>(x, w_qkv, w_out, xb, wqkvb, woutb);

  gemm_qkv<<<768, 256, 0, stream>>>(xb, wqkvb, Qd, Kdd, Vtd);
  attn_kernel<<<dim3(SEQ / 128 * 2, BATCH * NHEAD), 256, 0, stream>>>(Qd, Kdd, Vtd, OpA, OpB, LseA, LseB);
  merge_kernel<<<dim3(SEQ / 64, BATCH * NHEAD), 256, 0, stream>>>(OpA, OpB, LseA, LseB, Od);
  gemm_out<<<512, 256, 0, stream>>>(Od, woutb, b_out, (float*)d_out);
}

// Round 22
// 115.922 us; speedup vs baseline: 1.1133x; 1.1133x over previous
//
#include <hip/hip_runtime.h>
#include <hip/hip_bf16.h>
#include <stdint.h>

typedef unsigned short u16;
typedef short bf16x8 __attribute__((ext_vector_type(8)));
typedef float f32x4 __attribute__((ext_vector_type(4)));
typedef float f32x16 __attribute__((ext_vector_type(16)));
typedef u16 u16x4 __attribute__((ext_vector_type(4)));
typedef unsigned int uint2v __attribute__((ext_vector_type(2)));

#define DIMX  1024
#define NHEAD 16
#define DH    64
#define INNER 1024
#define BATCH 2
#define SEQ   2048
#define MTOT  (BATCH*SEQ)   /* 4096 */
#define EQKV  (3*INNER)     /* 3072 */
// frag-shuffled K/V layout: [bh][t(32)][c(2)][kd(4)][lane(64)][e(8)] bf16
#define HSTRIDE 131072      /* elems per head = SEQ*DH */
#define TSTRIDE 4096        /* elems per 64-kv tile */

__device__ __forceinline__ u16 f2bf(float f) {
  unsigned int x = __float_as_uint(f);
  unsigned int r = (x + 0x7FFFu + ((x >> 16) & 1u)) >> 16;
  return (u16)r;
}

__device__ __forceinline__ unsigned int cvtpk(float lo, float hi) {
  unsigned int r;
  asm("v_cvt_pk_bf16_f32 %0, %1, %2" : "=v"(r) : "v"(lo), "v"(hi));
  return r;
}

__device__ __forceinline__ void plswap_u(unsigned int& x, unsigned int& y) {
  auto r = __builtin_amdgcn_permlane32_swap(x, y, false, false);
  x = r[0]; y = r[1];
}
__device__ __forceinline__ void plswap_f2(float v, float& a, float& b) {
  unsigned int x = __float_as_uint(v), y = __float_as_uint(v);
  auto r = __builtin_amdgcn_permlane32_swap(x, y, false, false);
  a = __uint_as_float(r[0]); b = __uint_as_float(r[1]);
}

__device__ __forceinline__ void async16(void* lds, const void* g) {
  __builtin_amdgcn_global_load_lds(
      (const __attribute__((address_space(1))) unsigned int*)g,
      (__attribute__((address_space(3))) unsigned int*)lds,
      16, 0, 0);
}

// staging swizzle (BK=32 GEMMs): 4 16B-units per 32-col row, unit ^= S(r)
__device__ __forceinline__ int swz4(int r) { return (r ^ (r >> 2)) & 3; }

// ---------------- fused fp32 -> bf16 convert (one launch, three tensors) ----------------
#define X4C (MTOT * DIMX / 4)
#define W4C (EQKV * DIMX / 4)
#define O4C (DIMX * INNER / 4)
__global__ void cvt_all(const float* __restrict__ x, const float* __restrict__ wq,
                        const float* __restrict__ wo, u16* __restrict__ xb,
                        u16* __restrict__ wqb, u16* __restrict__ wob) {
  int i = blockIdx.x * blockDim.x + threadIdx.x;
  const float* src; u16* dst; int off;
  if (i < X4C)            { src = x;  dst = xb;  off = i; }
  else if (i < X4C + W4C) { src = wq; dst = wqb; off = i - X4C; }
  else                    { src = wo; dst = wob; off = i - X4C - W4C; }
  float4 v = ((const float4*)src)[off];
  u16x4 o;
  o[0] = f2bf(v.x); o[1] = f2bf(v.y); o[2] = f2bf(v.z); o[3] = f2bf(v.w);
  ((u16x4*)dst)[off] = o;
}

// ---------------- QKV projection GEMM (r18 fenced pipeline; K/V epilogues write frag order) ----------------
__global__ __launch_bounds__(256) void gemm_qkv(const u16* __restrict__ X, const u16* __restrict__ W,
                                                u16* __restrict__ Qo, u16* __restrict__ Ko,
                                                u16* __restrict__ Vt) {
  __shared__ short sAll[24576];      // 48 KB: sA[3][4096] + sB[3][4096]
  short* sA = sAll;
  short* sB = sAll + 12288;
  const int tid = threadIdx.x;
  const int wv = tid >> 6, l = tid & 63;
  const int lo = l & 15, hi = l >> 4;
  const int wr = wv >> 1, wc = wv & 1;

  int lin = blockIdx.x;
  int wgid = (lin & 7) * 96 + (lin >> 3);
  const int bx = wgid / 32;
  const int by = wgid % 32;
  const int tn = bx * 128, tm = by * 128;

  f32x4 acc[4][4];
#pragma unroll
  for (int i = 0; i < 4; i++)
#pragma unroll
    for (int j = 0; j < 4; j++) acc[i][j] = (f32x4){0.f, 0.f, 0.f, 0.f};

  auto stageT = [&](int buf, int kt) {
    int k0 = kt * 32;
    int off = buf * 4096;
#pragma unroll
    for (int c = 0; c < 2; c++) {
      int R0 = wv * 32 + c * 16;
      int r = R0 + (l >> 2);
      int sc = ((l & 3) ^ swz4(r)) * 8;
      async16(&sA[off + R0 * 32], &X[(size_t)(tm + r) * DIMX + k0 + sc]);
      async16(&sB[off + R0 * 32], &W[(size_t)(tn + r) * DIMX + k0 + sc]);
    }
  };

  auto compute = [&](int buf) {
    bf16x8 af[4], bf[4];
#pragma unroll
    for (int i = 0; i < 4; i++) {
      int r = wr * 64 + i * 16 + lo;
      af[i] = *(const bf16x8*)&sA[buf * 4096 + r * 32 + ((hi ^ swz4(r)) * 8)];
    }
#pragma unroll
    for (int j = 0; j < 4; j++) {
      int r = wc * 64 + j * 16 + lo;
      bf[j] = *(const bf16x8*)&sB[buf * 4096 + r * 32 + ((hi ^ swz4(r)) * 8)];
    }
#pragma unroll
    for (int i = 0; i < 4; i++)
#pragma unroll
      for (int j = 0; j < 4; j++)
        acc[i][j] = __builtin_amdgcn_mfma_f32_16x16x32_bf16(af[i], bf[j], acc[i][j], 0, 0, 0);
  };

  const int NT = DIMX / 32;   // 32
  stageT(0, 0);
  stageT(1, 1);
  int bc = 0;
  for (int kt = 0; kt < NT - 2; kt++) {
    int bs = bc + 2; if (bs >= 3) bs -= 3;
    stageT(bs, kt + 2);
    asm volatile("s_waitcnt vmcnt(8)" ::: "memory");
    asm volatile("s_barrier" ::: "memory");
    __builtin_amdgcn_sched_barrier(0);
    compute(bc);
    __builtin_amdgcn_sched_barrier(0);
    asm volatile("s_barrier" ::: "memory");
    bc = (bc == 2) ? 0 : bc + 1;
  }
  asm volatile("s_waitcnt vmcnt(4)" ::: "memory");
  asm volatile("s_barrier" ::: "memory");
  __builtin_amdgcn_sched_barrier(0);
  compute(bc);
  __builtin_amdgcn_sched_barrier(0);
  asm volatile("s_barrier" ::: "memory");
  bc = (bc == 2) ? 0 : bc + 1;
  asm volatile("s_waitcnt vmcnt(0)" ::: "memory");
  asm volatile("s_barrier" ::: "memory");
  __builtin_amdgcn_sched_barrier(0);
  compute(bc);
  __builtin_amdgcn_sched_barrier(0);
  __syncthreads();

  const int cls = tn >> 10;
  const float scale = 0.125f * 1.44269504088896f;  // dh^-0.5 * log2(e)

  if (cls == 0) {
    // Q: [bh][n][64] layout, paired converts
#pragma unroll
    for (int i = 0; i < 4; i++) {
      int mbase = tm + wr * 64 + i * 16 + hi * 4;
#pragma unroll
      for (int j = 0; j < 4; j++) {
        int e = tn + wc * 64 + j * 16 + lo;
        int h = e >> 6, d = e & 63;
        size_t a0 = (((size_t)((mbase >> 11) * NHEAD + h)) * SEQ) * DH + d;
#pragma unroll
        for (int rp = 0; rp < 2; rp++) {
          int n0 = (mbase + rp * 2) & 2047;
          unsigned int pk = cvtpk(acc[i][j][rp * 2] * scale, acc[i][j][rp * 2 + 1] * scale);
          Qo[a0 + (size_t)n0 * DH] = (u16)pk;
          Qo[a0 + (size_t)(n0 + 1) * DH] = (u16)(pk >> 16);
        }
      }
    }
  } else if (cls == 1) {
    // K: frag-shuffled scatter [bh][t][c][kd][lane][e]
#pragma unroll
    for (int i = 0; i < 4; i++) {
      int mbase = tm + wr * 64 + i * 16 + hi * 4;
      int b = mbase >> 11;
#pragma unroll
      for (int j = 0; j < 4; j++) {
        int e2 = (tn + wc * 64 + j * 16 + lo) - 1024;
        int h = e2 >> 6, d = e2 & 63;
        int kd = d >> 4, hi5k = (d >> 3) & 1, e8 = d & 7;
        size_t hb = (size_t)(b * NHEAD + h) * HSTRIDE + (size_t)kd * 512 + hi5k * 256 + e8;
#pragma unroll
        for (int rp = 0; rp < 2; rp++) {
          int n0 = (mbase + rp * 2) & 2047;          // even
          int t_ = n0 >> 6, kvi = n0 & 63;
          int c = kvi >> 5, l31k = kvi & 31;
          unsigned int pk = cvtpk(acc[i][j][rp * 2], acc[i][j][rp * 2 + 1]);
          size_t a = hb + (size_t)t_ * TSTRIDE + c * 2048 + l31k * 8;
          Ko[a] = (u16)pk;
          Ko[a + 8] = (u16)(pk >> 16);               // n0+1 -> lane+1
        }
      }
    }
  } else {
    // V: LDS bounce, then exact 16B frag-slot writes
#pragma unroll
    for (int i = 0; i < 4; i++) {
#pragma unroll
      for (int j = 0; j < 4; j++) {
        int e = wc * 64 + j * 16 + lo;
#pragma unroll
        for (int rp = 0; rp < 2; rp++) {
          int n = wr * 64 + i * 16 + hi * 4 + rp * 2;
          unsigned int pk = cvtpk(acc[i][j][rp * 2], acc[i][j][rp * 2 + 1]);
          *(unsigned int*)&sAll[e * 128 + (((n >> 3) ^ (e & 15)) * 8) + (n & 7)] = pk;
        }
      }
    }
    __syncthreads();
    int er = tid >> 1, half = tid & 1;
    int e2 = tn + er - 2048;
    int h = e2 >> 6, dv = e2 & 63;
    int b = tm >> 11, nb = tm & 2047;
    int c = dv >> 5, l31v = dv & 31;
    size_t vb = (size_t)(b * NHEAD + h) * HSTRIDE
              + (size_t)((nb >> 6) + half) * TSTRIDE + (size_t)c * 2048 + l31v * 8;
#pragma unroll
    for (int k = 0; k < 8; k++) {
      int phys = (half * 8 + k) ^ (er & 15);
      bf16x8 v = *(const bf16x8*)&sAll[er * 128 + phys * 8];
      int ks = k >> 1, hi5v = k & 1;
      *(bf16x8*)&Vt[vb + ks * 512 + hi5v * 256] = v;
    }
  }
}

// ---------------- flash attention (frag-shuffled direct-L2, barrier-free, reg-pipelined) ----------------
// Q: [bh][n][64] (pre-scaled); Ksh/Vsh: frag order [bh][t][c][kd|ks][lane][8].
// Each frag load = one coalesced global_load_dwordx4. No LDS, no barriers;
// K(t+1) reg-prefetch, V(t) issued before QK^T. (round-20 proven, 49.8 us)
__global__ __launch_bounds__(256) void attn_kernel(const u16* __restrict__ Q, const u16* __restrict__ Ksh,
                                                   const u16* __restrict__ Vsh, u16* __restrict__ O) {
  const int tid = threadIdx.x, wv = tid >> 6, l = tid & 63;
  const int l31 = l & 31, hi5 = l >> 5;

  int lin = blockIdx.y * gridDim.x + blockIdx.x;
  int wgid = (lin & 7) * 64 + (lin >> 3);
  int bx = wgid & 15;
  int bh = wgid >> 4;

  const int qw = bx * 128 + wv * 32;
  const u16* Qb = Q + (size_t)bh * SEQ * DH;
  const u16* Kb = Ksh + (size_t)bh * HSTRIDE + l * 8;
  const u16* Vb = Vsh + (size_t)bh * HSTRIDE + l * 8;

  bf16x8 qf[4];
#pragma unroll
  for (int kd = 0; kd < 4; kd++)
    qf[kd] = *(const bf16x8*)&Qb[(size_t)(qw + l31) * DH + kd * 16 + hi5 * 8];

  f32x16 o0, o1;
#pragma unroll
  for (int r = 0; r < 16; r++) { o0[r] = 0.f; o1[r] = 0.f; }
  float lsum = 0.f;
  const float CSHIFT = 12.0f;

  bf16x8 kA0[4], kA1[4], kB0[4], kB1[4];

  auto loadK = [&](bf16x8 (&k0)[4], bf16x8 (&k1)[4], int t) {
    const u16* p = Kb + (size_t)t * TSTRIDE;
#pragma unroll
    for (int kd = 0; kd < 4; kd++) {
      k0[kd] = *(const bf16x8*)&p[kd * 512];
      k1[kd] = *(const bf16x8*)&p[2048 + kd * 512];
    }
  };

  auto tile = [&](bf16x8 (&kc0)[4], bf16x8 (&kc1)[4],
                  bf16x8 (&kn0)[4], bf16x8 (&kn1)[4], int t) {
    // V(t): issued now, consumed after softmax
    const u16* pv = Vb + (size_t)t * TSTRIDE;
    bf16x8 vf0[4], vf1[4];
#pragma unroll
    for (int ks = 0; ks < 4; ks++) {
      vf0[ks] = *(const bf16x8*)&pv[ks * 512];
      vf1[ks] = *(const bf16x8*)&pv[2048 + ks * 512];
    }
    // K(t+1) into alternate reg set (full-tile latency cover)
    if (t + 1 < SEQ / 64) loadK(kn0, kn1, t + 1);

    // ---- S^T = K Q^T - CSHIFT ----
    f32x16 s0, s1;
#pragma unroll
    for (int r = 0; r < 16; r++) { s0[r] = -CSHIFT; s1[r] = -CSHIFT; }
#pragma unroll
    for (int kd = 0; kd < 4; kd++) {
      s0 = __builtin_amdgcn_mfma_f32_32x32x16_bf16(kc0[kd], qf[kd], s0, 0, 0, 0);
      s1 = __builtin_amdgcn_mfma_f32_32x32x16_bf16(kc1[kd], qf[kd], s1, 0, 0, 0);
    }

    // ---- bounded softmax: P = exp2(S - 12), no max tracking ----
    float sm[16];
#pragma unroll
    for (int r = 0; r < 16; r++) {
      s0[r] = __builtin_amdgcn_exp2f(s0[r]);
      s1[r] = __builtin_amdgcn_exp2f(s1[r]);
      sm[r] = s0[r] + s1[r];
    }
#pragma unroll
    for (int st = 8; st > 0; st >>= 1)
#pragma unroll
      for (int r = 0; r < st; r++) sm[r] += sm[r + st];
    lsum += sm[0];

    // ---- P -> PV B-frags via cvt_pk + permlane32_swap ----
    bf16x8 pa[4];
#pragma unroll
    for (int ks = 0; ks < 4; ks++) {
      const int sft = (ks & 1) * 8;
      float e0 = (ks < 2) ? s0[sft + 0] : s1[sft + 0];
      float e1 = (ks < 2) ? s0[sft + 1] : s1[sft + 1];
      float e2 = (ks < 2) ? s0[sft + 2] : s1[sft + 2];
      float e3 = (ks < 2) ? s0[sft + 3] : s1[sft + 3];
      float e4 = (ks < 2) ? s0[sft + 4] : s1[sft + 4];
      float e5 = (ks < 2) ? s0[sft + 5] : s1[sft + 5];
      float e6 = (ks < 2) ? s0[sft + 6] : s1[sft + 6];
      float e7 = (ks < 2) ? s0[sft + 7] : s1[sft + 7];
      unsigned int w0 = cvtpk(e0, e1);
      unsigned int w1 = cvtpk(e2, e3);
      unsigned int w2 = cvtpk(e4, e5);
      unsigned int w3 = cvtpk(e6, e7);
      plswap_u(w0, w2);
      plswap_u(w1, w3);
      union { unsigned int w[4]; bf16x8 v; } u;
      u.w[0] = w0; u.w[1] = w1; u.w[2] = w2; u.w[3] = w3;
      pa[ks] = u.v;
    }

    // ---- O^T += V^T P^T ----
#pragma unroll
    for (int ks = 0; ks < 4; ks++) {
      o0 = __builtin_amdgcn_mfma_f32_32x32x16_bf16(vf0[ks], pa[ks], o0, 0, 0, 0);
      o1 = __builtin_amdgcn_mfma_f32_32x32x16_bf16(vf1[ks], pa[ks], o1, 0, 0, 0);
    }
  };

  loadK(kA0, kA1, 0);
  for (int t = 0; t < SEQ / 64; t += 2) {
    tile(kA0, kA1, kB0, kB1, t);
    tile(kB0, kB1, kA0, kA1, t + 1);
  }

  // ---- finalize: combine partner lsum, normalize, store ----
  float la, lb;
  plswap_f2(lsum, la, lb);
  float inv = 1.0f / (la + lb);

  int b = bh >> 4, h = bh & 15;
  int q = qw + l31;
  size_t orow = ((size_t)(b * SEQ + q)) * INNER + h * 64;
#pragma unroll
  for (int half = 0; half < 2; half++) {
    const f32x16& oo = half ? o1 : o0;
#pragma unroll
    for (int g = 0; g < 4; g++) {
      uint2v pk2;
      pk2[0] = cvtpk(oo[g * 4 + 0] * inv, oo[g * 4 + 1] * inv);
      pk2[1] = cvtpk(oo[g * 4 + 2] * inv, oo[g * 4 + 3] * inv);
      int dv = half * 32 + g * 8 + 4 * hi5;
      *(uint2v*)&O[orow + dv] = pk2;
    }
  }
}

// ---------------- output projection GEMM (128x64 tile, 512 blocks = 2/CU, dbuf — r17 proven) ----------------
__global__ __launch_bounds__(256) void gemm_out(const u16* __restrict__ A, const u16* __restrict__ W,
                                                const float* __restrict__ bias, float* __restrict__ out) {
  __shared__ short sAll[12288];      // sA[2][4096] + sB[2][2048]  (24 KB)
  short* sA = sAll;
  short* sB = sAll + 8192;
  const int tid = threadIdx.x;
  const int wv = tid >> 6, l = tid & 63;
  const int lo = l & 15, hi = l >> 4;
  const int wr = wv >> 1, wc = wv & 1;

  int lin = blockIdx.x;
  int wgid = (lin & 7) * 64 + (lin >> 3);
  const int bx = wgid / 32;          // N-tile 0..15
  const int by = wgid % 32;          // M-tile 0..31
  const int tn = bx * 64, tm = by * 128;

  f32x4 acc[4][2];
#pragma unroll
  for (int i = 0; i < 4; i++)
#pragma unroll
    for (int j = 0; j < 2; j++) acc[i][j] = (f32x4){0.f, 0.f, 0.f, 0.f};

  auto stage = [&](int buf, int kt) {
    int k0 = kt * 32;
#pragma unroll
    for (int c = 0; c < 2; c++) {
      int R0 = wv * 32 + c * 16;
      int r = R0 + (l >> 2);
      int sc = ((l & 3) ^ swz4(r)) * 8;
      async16(&sA[buf * 4096 + R0 * 32], &A[(size_t)(tm + r) * INNER + k0 + sc]);
    }
    int rB = wv * 16 + (l >> 2);
    int scB = ((l & 3) ^ swz4(rB)) * 8;
    async16(&sB[buf * 2048 + (wv * 16) * 32], &W[(size_t)(tn + rB) * INNER + k0 + scB]);
  };

  stage(0, 0);
  __syncthreads();

  for (int kt = 0; kt < INNER / 32; kt++) {
    const int buf = kt & 1;
    if (kt + 1 < INNER / 32) stage(buf ^ 1, kt + 1);
    bf16x8 af[4], bf[2];
#pragma unroll
    for (int i = 0; i < 4; i++) {
      int r = wr * 64 + i * 16 + lo;
      af[i] = *(const bf16x8*)&sA[buf * 4096 + r * 32 + ((hi ^ swz4(r)) * 8)];
    }
#pragma unroll
    for (int j = 0; j < 2; j++) {
      int r = wc * 32 + j * 16 + lo;
      bf[j] = *(const bf16x8*)&sB[buf * 2048 + r * 32 + ((hi ^ swz4(r)) * 8)];
    }
#pragma unroll
    for (int i = 0; i < 4; i++)
#pragma unroll
      for (int j = 0; j < 2; j++)
        acc[i][j] = __builtin_amdgcn_mfma_f32_16x16x32_bf16(af[i], bf[j], acc[i][j], 0, 0, 0);
    __syncthreads();
  }

#pragma unroll
  for (int i = 0; i < 4; i++) {
    int mbase = tm + wr * 64 + i * 16 + hi * 4;
#pragma unroll
    for (int j = 0; j < 2; j++) {
      int col = tn + wc * 32 + j * 16 + lo;
      float bv = bias[col];
#pragma unroll
      for (int r = 0; r < 4; r++)
        out[(size_t)(mbase + r) * DIMX + col] = acc[i][j][r] + bv;
    }
  }
}

extern "C" void kernel_launch(void* const* d_in, const int* in_sizes, int n_in,
                              void* d_out, int out_size, void* d_ws, size_t ws_size,
                              hipStream_t stream) {
  const float* x     = (const float*)d_in[0];
  const float* w_qkv = (const float*)d_in[1];
  const float* w_out = (const float*)d_in[2];
  const float* b_out = (const float*)d_in[3];

  char* ws = (char*)d_ws;
  u16* xb    = (u16*)(ws);                         // 8 MB
  u16* wqkvb = (u16*)(ws + (size_t)8  * (1<<20));  // 6 MB
  u16* woutb = (u16*)(ws + (size_t)14 * (1<<20));  // 2 MB
  u16* Qd    = (u16*)(ws + (size_t)16 * (1<<20));  // 8 MB
  u16* Kdd   = (u16*)(ws + (size_t)24 * (1<<20));  // 8 MB (frag-shuffled)
  u16* Vtd   = (u16*)(ws + (size_t)32 * (1<<20));  // 8 MB (frag-shuffled)
  u16* Od    = (u16*)(ws + (size_t)40 * (1<<20));  // 8 MB

  cvt_all<<<(X4C + W4C + O4C) / 256, 256, 0, stream>>>(x, w_qkv, w_out, xb, wqkvb, woutb);

  gemm_qkv<<<768, 256, 0, stream>>>(xb, wqkvb, Qd, Kdd, Vtd);
  attn_kernel<<<dim3(SEQ / 128, BATCH * NHEAD), 256, 0, stream>>>(Qd, Kdd, Vtd, Od);
  gemm_out<<<512, 256, 0, stream>>>(Od, woutb, b_out, (float*)d_out);
}